// Round 4
// baseline (118.372 us; speedup 1.0000x reference)
//
#include <hip/hip_runtime.h>
#include <hip/hip_cooperative_groups.h>
#include <math.h>

namespace cg = cooperative_groups;

#define NB 32          // batch
#define NM 32          // max GT per image
#define NA 3           // anchors per scale
#define NCLS 80
#define NCH 85         // 5 + C
#define IOU_THR 0.7f
#define L_COORD 0.75f
#define FEPS 1e-8f

// task layout
#define NOOBJ0_TASKS (NB * NA * 1)    // G=13: 169 -> 1 chunk of 256
#define NOOBJ1_TASKS (NB * NA * 3)    // G=26: 676 -> 3 chunks
#define NOOBJ2_TASKS (NB * NA * 11)   // G=52: 2704 -> 11 chunks
#define OFF1 (NOOBJ0_TASKS)                        // 96
#define OFF2 (OFF1 + NOOBJ1_TASKS)                 // 384
#define OFFM (OFF2 + NOOBJ2_TASKS)                 // 1440
#define MATCHED_TASKS (3 * NB * NM / 4)            // 3072 wave-tasks / 4 waves = 768
#define TOTAL_TASKS (OFFM + MATCHED_TASKS)         // 2208
#define GRID_C 736                                 // 2208 / 3 tasks per block

struct Smem {
    float sx1[NM], sy1[NM], sx2[NM], sy2[NM], sarea[NM];
    int   scode[NM];
    float wsum[4];
};

__device__ __forceinline__ float sigmoidf_(float x) {
    return 1.0f / (1.0f + expf(-x));
}

// argmax over 9 anchors of min-intersection IoU (first-max tie, like jnp.argmax)
__device__ __forceinline__ int best_prior(const float* __restrict__ anchors,
                                          float w, float h, float area_g) {
    float best = -1.0f;
    int bp = 0;
    #pragma unroll
    for (int k = 0; k < 9; ++k) {
        float aw = anchors[k * 2 + 0];
        float ah = anchors[k * 2 + 1];
        float inter = fminf(w, aw) * fminf(h, ah);
        float uni = area_g + aw * ah - inter;
        float r = inter / (uni + FEPS);
        if (r > best) { best = r; bp = k; }
    }
    return bp;
}

// ---------------------------------------------------------------------------
// noobj body: one task = (b, a, chunk) of scale S. Recomputes the 32 GT
// entries of batch b inline, per-cell positivity test, returns block partial.
// ---------------------------------------------------------------------------
template <int G, int S>
__device__ float noobj_body(const float* __restrict__ p,
                            const float* __restrict__ gt_boxes,
                            const float* __restrict__ anchors,
                            int bid, Smem& sm) {
    constexpr int GG = G * G;
    constexpr int CHUNKS = (GG + 255) / 256;

    int chunk = bid % CHUNKS;
    int a = (bid / CHUNKS) % NA;
    int b = bid / (CHUNKS * NA);
    int tid = threadIdx.x;

    if (tid < NM) {
        int e = b * NM + tid;
        float cx = gt_boxes[e * 4 + 0];
        float cy = gt_boxes[e * 4 + 1];
        float w  = gt_boxes[e * 4 + 2];
        float h  = gt_boxes[e * 4 + 3];
        float x1 = cx - w * 0.5f, y1 = cy - h * 0.5f;
        float x2 = cx + w * 0.5f, y2 = cy + h * 0.5f;
        sm.sx1[tid] = x1; sm.sy1[tid] = y1;
        sm.sx2[tid] = x2; sm.sy2[tid] = y2;
        sm.sarea[tid] = (x2 - x1) * (y2 - y1);
        int bp = best_prior(anchors, w, h, w * h);
        int code = -1;
        if (bp >= S * NA && bp < S * NA + NA) {
            float gxf = fminf(fmaxf(floorf(cx * (float)G), 0.0f), (float)(G - 1));
            float gyf = fminf(fmaxf(floorf(cy * (float)G), 0.0f), (float)(G - 1));
            code = (bp - S * NA) * GG + (int)gyf * G + (int)gxf;
        }
        sm.scode[tid] = code;
    }
    __syncthreads();

    float aw = anchors[(S * NA + a) * 2 + 0];
    float ah = anchors[(S * NA + a) * 2 + 1];

    int pix = chunk * 256 + tid;
    float local = 0.0f;
    if (pix < GG) {
        int gy = pix / G, gx = pix % G;
        const float* base = p + (size_t)(b * (NA * NCH) + a * NCH) * GG + pix;
        float tx = base[0];
        float ty = base[(size_t)GG];
        float tw = base[2 * (size_t)GG];
        float th = base[3 * (size_t)GG];
        float to = base[4 * (size_t)GG];

        float bcx = (sigmoidf_(tx) + (float)gx) / (float)G;
        float bcy = (sigmoidf_(ty) + (float)gy) / (float)G;
        float bw = aw * expf(tw);
        float bh = ah * expf(th);
        float bx1 = bcx - bw * 0.5f, by1 = bcy - bh * 0.5f;
        float bx2 = bcx + bw * 0.5f, by2 = bcy + bh * 0.5f;
        float areab = (bx2 - bx1) * (by2 - by1);

        int mycode = a * GG + pix;
        bool pos = false;
        #pragma unroll 8
        for (int m = 0; m < NM; ++m) {
            float ltx = fmaxf(sm.sx1[m], bx1), lty = fmaxf(sm.sy1[m], by1);
            float rbx = fminf(sm.sx2[m], bx2), rby = fminf(sm.sy2[m], by2);
            float wx = fmaxf(rbx - ltx, 0.0f), wy = fmaxf(rby - lty, 0.0f);
            float inter = wx * wy;
            float denom = sm.sarea[m] + areab - inter + FEPS;
            pos = pos || (inter > IOU_THR * denom);   // iou > THR (denom > 0)
            pos = pos || (sm.scode[m] == mycode);     // matched-cell override
        }
        if (!pos) {
            float so = sigmoidf_(to);
            local = so * so;
        }
    }

    // block reduce: wave shuffle -> LDS
    for (int off = 32; off; off >>= 1) local += __shfl_down(local, off);
    if ((tid & 63) == 0) sm.wsum[tid >> 6] = local;
    __syncthreads();
    return sm.wsum[0] + sm.wsum[1] + sm.wsum[2] + sm.wsum[3];
}

// ---------------------------------------------------------------------------
// matched body: one wave per (scale, b, m) entry; 4 waves per task.
// Lane covers channels {lane, lane+64}. Returns block partial.
// ---------------------------------------------------------------------------
__device__ float matched_body(const float* __restrict__ p0,
                              const float* __restrict__ p1,
                              const float* __restrict__ p2,
                              const float* __restrict__ gt_boxes,
                              const int* __restrict__ gt_classes,
                              const float* __restrict__ anchors,
                              int mb, Smem& sm) {
    int tid = threadIdx.x;
    int wave = tid >> 6, lane = tid & 63;
    int t = mb * 4 + wave;        // 0 .. 3071
    int s = t >> 10;              // scale: 1024 entries per scale
    int e = t & 1023;             // (b, m) flat
    int b = e >> 5;

    float cx = gt_boxes[e * 4 + 0];
    float cy = gt_boxes[e * 4 + 1];
    float w  = gt_boxes[e * 4 + 2];
    float h  = gt_boxes[e * 4 + 3];
    int bp = best_prior(anchors, w, h, w * h);
    int a = bp - s * NA;

    float term = 0.0f;
    if (a >= 0 && a < NA) {                       // mask_s (wave-uniform)
        const float* p = (s == 0) ? p0 : ((s == 1) ? p1 : p2);
        int G = (s == 0) ? 13 : ((s == 1) ? 26 : 52);
        long nboff = (s == 0) ? 0L : ((s == 1) ? 16224L : 81120L);
        int GG = G * G;

        float gxf = fminf(fmaxf(floorf(cx * (float)G), 0.0f), (float)(G - 1));
        float gyf = fminf(fmaxf(floorf(cy * (float)G), 0.0f), (float)(G - 1));
        int gx = (int)gxf, gy = (int)gyf;
        int box_idx = a * GG + gy * G + gx;
        long gidx = nboff + (long)b * (NA * GG) + box_idx;
        if (gidx != 0) {                          // valid (wave-uniform)
            float dx = cx * (float)G - gxf;
            float dy = cy * (float)G - gyf;
            float wgt = 2.0f - w * h;
            float twt = logf(fmaxf(w, FEPS)) - logf(anchors[bp * 2 + 0]);
            float tht = logf(fmaxf(h, FEPS)) - logf(anchors[bp * 2 + 1]);
            int cls = gt_classes[e];

            size_t cellbase = (size_t)(b * (NA * NCH) + a * NCH) * GG
                              + (size_t)(gy * G + gx);
            for (int ch = lane; ch < NCH; ch += 64) {
                float val = p[cellbase + (size_t)ch * GG];
                if (ch < 2) {
                    float sv = sigmoidf_(val);
                    float d = sv - (ch == 0 ? dx : dy);
                    term += L_COORD * wgt * d * d;
                } else if (ch < 4) {
                    float d = val - (ch == 2 ? twt : tht);
                    term += L_COORD * wgt * d * d;
                } else if (ch == 4) {
                    float sv = sigmoidf_(val);
                    term += (sv - 1.0f) * (sv - 1.0f);
                } else {
                    float sv = sigmoidf_(val);
                    float oh = ((ch - 5) == cls) ? 1.0f : 0.0f;
                    term += (sv - oh) * (sv - oh);
                }
            }
        }
    }

    // 64-lane wave reduce -> LDS -> block partial
    for (int off = 32; off; off >>= 1) term += __shfl_down(term, off);
    if (lane == 0) sm.wsum[wave] = term;
    __syncthreads();
    return sm.wsum[0] + sm.wsum[1] + sm.wsum[2] + sm.wsum[3];
}

__device__ __forceinline__ float do_task(int task,
        const float* __restrict__ p0, const float* __restrict__ p1,
        const float* __restrict__ p2, const float* __restrict__ gt_boxes,
        const int* __restrict__ gt_classes, const float* __restrict__ anchors,
        Smem& sm) {
    if (task < OFF1)      return noobj_body<13, 0>(p0, gt_boxes, anchors, task, sm);
    else if (task < OFF2) return noobj_body<26, 1>(p1, gt_boxes, anchors, task - OFF1, sm);
    else if (task < OFFM) return noobj_body<52, 2>(p2, gt_boxes, anchors, task - OFF2, sm);
    else return matched_body(p0, p1, p2, gt_boxes, gt_classes, anchors, task - OFFM, sm);
}

// ---------------------------------------------------------------------------
// Cooperative single-dispatch kernel: 736 blocks x 3 tasks, grid sync,
// block 0 reduces partials and stores the scalar.
// ---------------------------------------------------------------------------
__global__ __launch_bounds__(256, 4)
void yolo_all(const float* __restrict__ p0, const float* __restrict__ p1,
              const float* __restrict__ p2, const float* __restrict__ gt_boxes,
              const int* __restrict__ gt_classes, const float* __restrict__ anchors,
              float* __restrict__ partials, float* __restrict__ out) {
    __shared__ Smem sm;
    float acc = 0.0f;
    for (int task = blockIdx.x; task < TOTAL_TASKS; task += GRID_C) {
        acc += do_task(task, p0, p1, p2, gt_boxes, gt_classes, anchors, sm);
        __syncthreads();   // protect sm reuse across tasks (wsum read vs next write)
    }
    if (threadIdx.x == 0)
        __hip_atomic_store(&partials[blockIdx.x], acc,
                           __ATOMIC_RELAXED, __HIP_MEMORY_SCOPE_AGENT);
    cg::this_grid().sync();
    if (blockIdx.x == 0) {
        int tid = threadIdx.x;
        float s = 0.0f;
        for (int i = tid; i < GRID_C; i += 256)
            s += __hip_atomic_load(&partials[i],
                                   __ATOMIC_RELAXED, __HIP_MEMORY_SCOPE_AGENT);
        for (int off = 32; off; off >>= 1) s += __shfl_down(s, off);
        __shared__ float fsum[4];
        if ((tid & 63) == 0) fsum[tid >> 6] = s;
        __syncthreads();
        if (tid == 0) out[0] = fsum[0] + fsum[1] + fsum[2] + fsum[3];
    }
}

// ---------------------------------------------------------------------------
// Fallback path (proven round-3 kernels): fused partials + tiny reduce.
// ---------------------------------------------------------------------------
__global__ __launch_bounds__(256)
void yolo_fused(const float* __restrict__ p0, const float* __restrict__ p1,
                const float* __restrict__ p2, const float* __restrict__ gt_boxes,
                const int* __restrict__ gt_classes, const float* __restrict__ anchors,
                float* __restrict__ partials) {
    __shared__ Smem sm;
    float part = do_task(blockIdx.x, p0, p1, p2, gt_boxes, gt_classes, anchors, sm);
    if (threadIdx.x == 0) partials[blockIdx.x] = part;
}

__global__ __launch_bounds__(256)
void yolo_reduce(const float* __restrict__ partials, float* __restrict__ out) {
    int tid = threadIdx.x;
    float s = 0.0f;
    for (int i = tid; i < TOTAL_TASKS; i += 256) s += partials[i];
    for (int off = 32; off; off >>= 1) s += __shfl_down(s, off);
    __shared__ float wsum[4];
    if ((tid & 63) == 0) wsum[tid >> 6] = s;
    __syncthreads();
    if (tid == 0) out[0] = wsum[0] + wsum[1] + wsum[2] + wsum[3];
}

// ---------------------------------------------------------------------------
extern "C" void kernel_launch(void* const* d_in, const int* in_sizes, int n_in,
                              void* d_out, int out_size, void* d_ws, size_t ws_size,
                              hipStream_t stream) {
    const float* p0 = (const float*)d_in[0];
    const float* p1 = (const float*)d_in[1];
    const float* p2 = (const float*)d_in[2];
    const float* gt_boxes = (const float*)d_in[3];
    const int* gt_classes = (const int*)d_in[4];
    const float* anchors = (const float*)d_in[5];
    float* out = (float*)d_out;
    float* partials = (float*)d_ws;

    // Input-independent (deterministic) choice: cooperative path only if the
    // grid is guaranteed co-resident.
    int nb = 0;
    hipError_t oe = hipOccupancyMaxActiveBlocksPerMultiprocessor(&nb, yolo_all, 256, 0);
    if (oe == hipSuccess && nb >= 3) {   // 736 blocks / 256 CUs = 2.875 per CU
        void* args[] = { (void*)&p0, (void*)&p1, (void*)&p2, (void*)&gt_boxes,
                         (void*)&gt_classes, (void*)&anchors,
                         (void*)&partials, (void*)&out };
        hipLaunchCooperativeKernel((const void*)yolo_all, dim3(GRID_C), dim3(256),
                                   args, 0, stream);
    } else {
        yolo_fused<<<TOTAL_TASKS, 256, 0, stream>>>(p0, p1, p2, gt_boxes,
                                                    gt_classes, anchors, partials);
        yolo_reduce<<<1, 256, 0, stream>>>(partials, out);
    }
}

// Round 5
// 113.555 us; speedup vs baseline: 1.0424x; 1.0424x over previous
//
#include <hip/hip_runtime.h>
#include <math.h>

#define NB 32          // batch
#define NM 32          // max GT per image
#define NA 3           // anchors per scale
#define NCLS 80
#define NCH 85         // 5 + C
#define IOU_THR 0.7f
#define L_COORD 0.75f
#define FEPS 1e-8f

// task layout
#define NOOBJ0_TASKS (NB * NA * 1)    // G=13: 169 -> 1 chunk of 256
#define NOOBJ1_TASKS (NB * NA * 3)    // G=26: 676 -> 3 chunks
#define NOOBJ2_TASKS (NB * NA * 11)   // G=52: 2704 -> 11 chunks
#define OFF1 (NOOBJ0_TASKS)                        // 96
#define OFF2 (OFF1 + NOOBJ1_TASKS)                 // 384
#define OFFM (OFF2 + NOOBJ2_TASKS)                 // 1440
#define MATCHED_TASKS (3 * NB * NM / 4)            // 3072 wave-tasks / 4 waves = 768
#define TOTAL_TASKS (OFFM + MATCHED_TASKS)         // 2208

// ws layout (floats): partials[0..2207], counter u32 @2208, flag u64 @2210
#define CNT_IDX  2208
#define FLAG_IDX 2210
#define FLAG_MAGIC 0x7a3c55aa1ee7f00dULL

struct Smem {
    float sx1[NM], sy1[NM], sx2[NM], sy2[NM], sarea[NM];
    int   scode[NM];
    float wsum[4];
};

__device__ __forceinline__ float sigmoidf_(float x) {
    return 1.0f / (1.0f + expf(-x));
}

// argmax over 9 anchors of min-intersection IoU (first-max tie, like jnp.argmax)
__device__ __forceinline__ int best_prior(const float* __restrict__ anchors,
                                          float w, float h, float area_g) {
    float best = -1.0f;
    int bp = 0;
    #pragma unroll
    for (int k = 0; k < 9; ++k) {
        float aw = anchors[k * 2 + 0];
        float ah = anchors[k * 2 + 1];
        float inter = fminf(w, aw) * fminf(h, ah);
        float uni = area_g + aw * ah - inter;
        float r = inter / (uni + FEPS);
        if (r > best) { best = r; bp = k; }
    }
    return bp;
}

// ---------------------------------------------------------------------------
// noobj body: one task = (b, a, chunk) of scale S. Recomputes the 32 GT
// entries of batch b inline, per-cell positivity test, returns block partial.
// ---------------------------------------------------------------------------
template <int G, int S>
__device__ float noobj_body(const float* __restrict__ p,
                            const float* __restrict__ gt_boxes,
                            const float* __restrict__ anchors,
                            int bid, Smem& sm) {
    constexpr int GG = G * G;
    constexpr int CHUNKS = (GG + 255) / 256;

    int chunk = bid % CHUNKS;
    int a = (bid / CHUNKS) % NA;
    int b = bid / (CHUNKS * NA);
    int tid = threadIdx.x;

    if (tid < NM) {
        int e = b * NM + tid;
        float cx = gt_boxes[e * 4 + 0];
        float cy = gt_boxes[e * 4 + 1];
        float w  = gt_boxes[e * 4 + 2];
        float h  = gt_boxes[e * 4 + 3];
        float x1 = cx - w * 0.5f, y1 = cy - h * 0.5f;
        float x2 = cx + w * 0.5f, y2 = cy + h * 0.5f;
        sm.sx1[tid] = x1; sm.sy1[tid] = y1;
        sm.sx2[tid] = x2; sm.sy2[tid] = y2;
        sm.sarea[tid] = (x2 - x1) * (y2 - y1);
        int bp = best_prior(anchors, w, h, w * h);
        int code = -1;
        if (bp >= S * NA && bp < S * NA + NA) {
            float gxf = fminf(fmaxf(floorf(cx * (float)G), 0.0f), (float)(G - 1));
            float gyf = fminf(fmaxf(floorf(cy * (float)G), 0.0f), (float)(G - 1));
            code = (bp - S * NA) * GG + (int)gyf * G + (int)gxf;
        }
        sm.scode[tid] = code;
    }
    __syncthreads();

    float aw = anchors[(S * NA + a) * 2 + 0];
    float ah = anchors[(S * NA + a) * 2 + 1];

    int pix = chunk * 256 + tid;
    float local = 0.0f;
    if (pix < GG) {
        int gy = pix / G, gx = pix % G;
        const float* base = p + (size_t)(b * (NA * NCH) + a * NCH) * GG + pix;
        float tx = base[0];
        float ty = base[(size_t)GG];
        float tw = base[2 * (size_t)GG];
        float th = base[3 * (size_t)GG];
        float to = base[4 * (size_t)GG];

        float bcx = (sigmoidf_(tx) + (float)gx) / (float)G;
        float bcy = (sigmoidf_(ty) + (float)gy) / (float)G;
        float bw = aw * expf(tw);
        float bh = ah * expf(th);
        float bx1 = bcx - bw * 0.5f, by1 = bcy - bh * 0.5f;
        float bx2 = bcx + bw * 0.5f, by2 = bcy + bh * 0.5f;
        float areab = (bx2 - bx1) * (by2 - by1);

        int mycode = a * GG + pix;
        bool pos = false;
        #pragma unroll 8
        for (int m = 0; m < NM; ++m) {
            float ltx = fmaxf(sm.sx1[m], bx1), lty = fmaxf(sm.sy1[m], by1);
            float rbx = fminf(sm.sx2[m], bx2), rby = fminf(sm.sy2[m], by2);
            float wx = fmaxf(rbx - ltx, 0.0f), wy = fmaxf(rby - lty, 0.0f);
            float inter = wx * wy;
            float denom = sm.sarea[m] + areab - inter + FEPS;
            pos = pos || (inter > IOU_THR * denom);   // iou > THR (denom > 0)
            pos = pos || (sm.scode[m] == mycode);     // matched-cell override
        }
        if (!pos) {
            float so = sigmoidf_(to);
            local = so * so;
        }
    }

    // block reduce: wave shuffle -> LDS
    for (int off = 32; off; off >>= 1) local += __shfl_down(local, off);
    if ((tid & 63) == 0) sm.wsum[tid >> 6] = local;
    __syncthreads();
    return sm.wsum[0] + sm.wsum[1] + sm.wsum[2] + sm.wsum[3];
}

// ---------------------------------------------------------------------------
// matched body: one wave per (scale, b, m) entry; 4 waves per task.
// Lane covers channels {lane, lane+64}. Returns block partial.
// ---------------------------------------------------------------------------
__device__ float matched_body(const float* __restrict__ p0,
                              const float* __restrict__ p1,
                              const float* __restrict__ p2,
                              const float* __restrict__ gt_boxes,
                              const int* __restrict__ gt_classes,
                              const float* __restrict__ anchors,
                              int mb, Smem& sm) {
    int tid = threadIdx.x;
    int wave = tid >> 6, lane = tid & 63;
    int t = mb * 4 + wave;        // 0 .. 3071
    int s = t >> 10;              // scale: 1024 entries per scale
    int e = t & 1023;             // (b, m) flat
    int b = e >> 5;

    float cx = gt_boxes[e * 4 + 0];
    float cy = gt_boxes[e * 4 + 1];
    float w  = gt_boxes[e * 4 + 2];
    float h  = gt_boxes[e * 4 + 3];
    int bp = best_prior(anchors, w, h, w * h);
    int a = bp - s * NA;

    float term = 0.0f;
    if (a >= 0 && a < NA) {                       // mask_s (wave-uniform)
        const float* p = (s == 0) ? p0 : ((s == 1) ? p1 : p2);
        int G = (s == 0) ? 13 : ((s == 1) ? 26 : 52);
        long nboff = (s == 0) ? 0L : ((s == 1) ? 16224L : 81120L);
        int GG = G * G;

        float gxf = fminf(fmaxf(floorf(cx * (float)G), 0.0f), (float)(G - 1));
        float gyf = fminf(fmaxf(floorf(cy * (float)G), 0.0f), (float)(G - 1));
        int gx = (int)gxf, gy = (int)gyf;
        int box_idx = a * GG + gy * G + gx;
        long gidx = nboff + (long)b * (NA * GG) + box_idx;
        if (gidx != 0) {                          // valid (wave-uniform)
            float dx = cx * (float)G - gxf;
            float dy = cy * (float)G - gyf;
            float wgt = 2.0f - w * h;
            float twt = logf(fmaxf(w, FEPS)) - logf(anchors[bp * 2 + 0]);
            float tht = logf(fmaxf(h, FEPS)) - logf(anchors[bp * 2 + 1]);
            int cls = gt_classes[e];

            size_t cellbase = (size_t)(b * (NA * NCH) + a * NCH) * GG
                              + (size_t)(gy * G + gx);
            for (int ch = lane; ch < NCH; ch += 64) {
                float val = p[cellbase + (size_t)ch * GG];
                if (ch < 2) {
                    float sv = sigmoidf_(val);
                    float d = sv - (ch == 0 ? dx : dy);
                    term += L_COORD * wgt * d * d;
                } else if (ch < 4) {
                    float d = val - (ch == 2 ? twt : tht);
                    term += L_COORD * wgt * d * d;
                } else if (ch == 4) {
                    float sv = sigmoidf_(val);
                    term += (sv - 1.0f) * (sv - 1.0f);
                } else {
                    float sv = sigmoidf_(val);
                    float oh = ((ch - 5) == cls) ? 1.0f : 0.0f;
                    term += (sv - oh) * (sv - oh);
                }
            }
        }
    }

    // 64-lane wave reduce -> LDS -> block partial
    for (int off = 32; off; off >>= 1) term += __shfl_down(term, off);
    if (lane == 0) sm.wsum[wave] = term;
    __syncthreads();
    return sm.wsum[0] + sm.wsum[1] + sm.wsum[2] + sm.wsum[3];
}

__device__ __forceinline__ float do_task(int task,
        const float* __restrict__ p0, const float* __restrict__ p1,
        const float* __restrict__ p2, const float* __restrict__ gt_boxes,
        const int* __restrict__ gt_classes, const float* __restrict__ anchors,
        Smem& sm) {
    if (task < OFF1)      return noobj_body<13, 0>(p0, gt_boxes, anchors, task, sm);
    else if (task < OFF2) return noobj_body<26, 1>(p1, gt_boxes, anchors, task - OFF1, sm);
    else if (task < OFFM) return noobj_body<52, 2>(p2, gt_boxes, anchors, task - OFF2, sm);
    else return matched_body(p0, p1, p2, gt_boxes, gt_classes, anchors, task - OFFM, sm);
}

// ---------------------------------------------------------------------------
// Single-dispatch kernel with flag/counter completion protocol (no cg sync).
//  block 0 (first-dispatched): zero counter, release-store MAGIC flag, do its
//    task, spin until counter==2207, lower flag, reduce partials, store out.
//  workers: do task, publish partial, wait flag==MAGIC (guarantees counter
//    was zeroed), release-increment counter, exit (frees CU slot -> no
//    deadlock even with blocks beyond residency). Garbage/poison-safe:
//    64-bit MAGIC can't collide with 0xAA poison or stale values; bounded
//    spins (~50-100 ms) make a hang impossible in any pathological case.
// ---------------------------------------------------------------------------
__global__ __launch_bounds__(256)
void yolo_one(const float* __restrict__ p0, const float* __restrict__ p1,
              const float* __restrict__ p2, const float* __restrict__ gt_boxes,
              const int* __restrict__ gt_classes, const float* __restrict__ anchors,
              float* __restrict__ ws, float* __restrict__ out) {
    unsigned* cnt = (unsigned*)(ws + CNT_IDX);
    unsigned long long* flag = (unsigned long long*)(ws + FLAG_IDX);
    int bid = blockIdx.x, tid = threadIdx.x;

    if (bid == 0 && tid == 0) {
        __hip_atomic_store(cnt, 0u, __ATOMIC_RELAXED, __HIP_MEMORY_SCOPE_AGENT);
        __hip_atomic_store(flag, FLAG_MAGIC, __ATOMIC_RELEASE, __HIP_MEMORY_SCOPE_AGENT);
    }

    __shared__ Smem sm;
    float part = do_task(bid, p0, p1, p2, gt_boxes, gt_classes, anchors, sm);

    if (bid != 0) {
        if (tid == 0) {
            __hip_atomic_store(&ws[bid], part, __ATOMIC_RELAXED, __HIP_MEMORY_SCOPE_AGENT);
            long spins = 0;
            while (__hip_atomic_load(flag, __ATOMIC_ACQUIRE, __HIP_MEMORY_SCOPE_AGENT)
                       != FLAG_MAGIC && spins < (1L << 20)) {
                __builtin_amdgcn_s_sleep(2);
                ++spins;
            }
            // release: partial store above is visible before this increment is
            __hip_atomic_fetch_add(cnt, 1u, __ATOMIC_RELEASE, __HIP_MEMORY_SCOPE_AGENT);
        }
        return;
    }

    // block 0: own partial + completion wait + final reduce
    if (tid == 0) {
        __hip_atomic_store(&ws[0], part, __ATOMIC_RELAXED, __HIP_MEMORY_SCOPE_AGENT);
        long spins = 0;
        while (__hip_atomic_load(cnt, __ATOMIC_ACQUIRE, __HIP_MEMORY_SCOPE_AGENT)
                   < (unsigned)(TOTAL_TASKS - 1) && spins < (1L << 21)) {
            __builtin_amdgcn_s_sleep(2);
            ++spins;
        }
        // lower flag so next replay's workers wait for the fresh zeroed counter
        __hip_atomic_store(flag, 0ull, __ATOMIC_RELAXED, __HIP_MEMORY_SCOPE_AGENT);
    }
    __syncthreads();   // extend thread-0's acquire to the whole block

    float s = 0.0f;
    for (int i = tid; i < TOTAL_TASKS; i += 256)
        s += __hip_atomic_load(&ws[i], __ATOMIC_RELAXED, __HIP_MEMORY_SCOPE_AGENT);
    for (int off = 32; off; off >>= 1) s += __shfl_down(s, off);
    __shared__ float fsum[4];
    if ((tid & 63) == 0) fsum[tid >> 6] = s;
    __syncthreads();
    if (tid == 0) out[0] = fsum[0] + fsum[1] + fsum[2] + fsum[3];
}

// ---------------------------------------------------------------------------
extern "C" void kernel_launch(void* const* d_in, const int* in_sizes, int n_in,
                              void* d_out, int out_size, void* d_ws, size_t ws_size,
                              hipStream_t stream) {
    const float* p0 = (const float*)d_in[0];
    const float* p1 = (const float*)d_in[1];
    const float* p2 = (const float*)d_in[2];
    const float* gt_boxes = (const float*)d_in[3];
    const int* gt_classes = (const int*)d_in[4];
    const float* anchors = (const float*)d_in[5];
    float* out = (float*)d_out;
    float* ws = (float*)d_ws;

    yolo_one<<<TOTAL_TASKS, 256, 0, stream>>>(p0, p1, p2, gt_boxes,
                                              gt_classes, anchors, ws, out);
}

// Round 6
// 54.725 us; speedup vs baseline: 2.1630x; 2.0750x over previous
//
#include <hip/hip_runtime.h>
#include <math.h>

#define NB 32          // batch
#define NM 32          // max GT per image
#define NA 3           // anchors per scale
#define NCLS 80
#define NCH 85         // 5 + C
#define IOU_THR 0.7f
#define L_COORD 0.75f
#define FEPS 1e-8f

// task layout
#define NOOBJ0_TASKS (NB * NA * 1)    // G=13: 169 -> 1 chunk of 256
#define NOOBJ1_TASKS (NB * NA * 3)    // G=26: 676 -> 3 chunks
#define NOOBJ2_TASKS (NB * NA * 11)   // G=52: 2704 -> 11 chunks
#define OFF1 (NOOBJ0_TASKS)                        // 96
#define OFF2 (OFF1 + NOOBJ1_TASKS)                 // 384
#define OFFM (OFF2 + NOOBJ2_TASKS)                 // 1440
#define MATCHED_TASKS (3 * NB * NM / 4)            // 3072 wave-tasks / 4 waves = 768
#define TOTAL_TASKS (OFFM + MATCHED_TASKS)         // 2208
#define NBLK 552                                   // 2208 / 4 tasks per block

// ws layout (floats): acc @0, cnt u32 @2, flag u64 @4
#define ACC_IDX  0
#define CNT_IDX  2
#define FLAG_IDX 4
#define FLAG_MAGIC 0x7a3c55aa1ee7f00dULL

struct Smem {
    float sx1[NM], sy1[NM], sx2[NM], sy2[NM], sarea[NM];
    int   scode[NM];
    float wsum[4];
};

__device__ __forceinline__ float sigmoidf_(float x) {
    return 1.0f / (1.0f + expf(-x));
}

// argmax over 9 anchors of min-intersection IoU (first-max tie, like jnp.argmax)
__device__ __forceinline__ int best_prior(const float* __restrict__ anchors,
                                          float w, float h, float area_g) {
    float best = -1.0f;
    int bp = 0;
    #pragma unroll
    for (int k = 0; k < 9; ++k) {
        float aw = anchors[k * 2 + 0];
        float ah = anchors[k * 2 + 1];
        float inter = fminf(w, aw) * fminf(h, ah);
        float uni = area_g + aw * ah - inter;
        float r = inter / (uni + FEPS);
        if (r > best) { best = r; bp = k; }
    }
    return bp;
}

// ---------------------------------------------------------------------------
// noobj body: one task = (b, a, chunk) of scale S. Recomputes the 32 GT
// entries of batch b inline, per-cell positivity test, returns block partial.
// ---------------------------------------------------------------------------
template <int G, int S>
__device__ float noobj_body(const float* __restrict__ p,
                            const float* __restrict__ gt_boxes,
                            const float* __restrict__ anchors,
                            int bid, Smem& sm) {
    constexpr int GG = G * G;
    constexpr int CHUNKS = (GG + 255) / 256;

    int chunk = bid % CHUNKS;
    int a = (bid / CHUNKS) % NA;
    int b = bid / (CHUNKS * NA);
    int tid = threadIdx.x;

    if (tid < NM) {
        int e = b * NM + tid;
        float cx = gt_boxes[e * 4 + 0];
        float cy = gt_boxes[e * 4 + 1];
        float w  = gt_boxes[e * 4 + 2];
        float h  = gt_boxes[e * 4 + 3];
        float x1 = cx - w * 0.5f, y1 = cy - h * 0.5f;
        float x2 = cx + w * 0.5f, y2 = cy + h * 0.5f;
        sm.sx1[tid] = x1; sm.sy1[tid] = y1;
        sm.sx2[tid] = x2; sm.sy2[tid] = y2;
        sm.sarea[tid] = (x2 - x1) * (y2 - y1);
        int bp = best_prior(anchors, w, h, w * h);
        int code = -1;
        if (bp >= S * NA && bp < S * NA + NA) {
            float gxf = fminf(fmaxf(floorf(cx * (float)G), 0.0f), (float)(G - 1));
            float gyf = fminf(fmaxf(floorf(cy * (float)G), 0.0f), (float)(G - 1));
            code = (bp - S * NA) * GG + (int)gyf * G + (int)gxf;
        }
        sm.scode[tid] = code;
    }
    __syncthreads();

    float aw = anchors[(S * NA + a) * 2 + 0];
    float ah = anchors[(S * NA + a) * 2 + 1];

    int pix = chunk * 256 + tid;
    float local = 0.0f;
    if (pix < GG) {
        int gy = pix / G, gx = pix % G;
        const float* base = p + (size_t)(b * (NA * NCH) + a * NCH) * GG + pix;
        float tx = base[0];
        float ty = base[(size_t)GG];
        float tw = base[2 * (size_t)GG];
        float th = base[3 * (size_t)GG];
        float to = base[4 * (size_t)GG];

        float bcx = (sigmoidf_(tx) + (float)gx) / (float)G;
        float bcy = (sigmoidf_(ty) + (float)gy) / (float)G;
        float bw = aw * expf(tw);
        float bh = ah * expf(th);
        float bx1 = bcx - bw * 0.5f, by1 = bcy - bh * 0.5f;
        float bx2 = bcx + bw * 0.5f, by2 = bcy + bh * 0.5f;
        float areab = (bx2 - bx1) * (by2 - by1);

        int mycode = a * GG + pix;
        bool pos = false;
        #pragma unroll 8
        for (int m = 0; m < NM; ++m) {
            float ltx = fmaxf(sm.sx1[m], bx1), lty = fmaxf(sm.sy1[m], by1);
            float rbx = fminf(sm.sx2[m], bx2), rby = fminf(sm.sy2[m], by2);
            float wx = fmaxf(rbx - ltx, 0.0f), wy = fmaxf(rby - lty, 0.0f);
            float inter = wx * wy;
            float denom = sm.sarea[m] + areab - inter + FEPS;
            pos = pos || (inter > IOU_THR * denom);   // iou > THR (denom > 0)
            pos = pos || (sm.scode[m] == mycode);     // matched-cell override
        }
        if (!pos) {
            float so = sigmoidf_(to);
            local = so * so;
        }
    }

    // block reduce: wave shuffle -> LDS
    for (int off = 32; off; off >>= 1) local += __shfl_down(local, off);
    if ((tid & 63) == 0) sm.wsum[tid >> 6] = local;
    __syncthreads();
    return sm.wsum[0] + sm.wsum[1] + sm.wsum[2] + sm.wsum[3];
}

// ---------------------------------------------------------------------------
// matched body: one wave per (scale, b, m) entry; 4 waves per task.
// Lane covers channels {lane, lane+64}. Returns block partial.
// ---------------------------------------------------------------------------
__device__ float matched_body(const float* __restrict__ p0,
                              const float* __restrict__ p1,
                              const float* __restrict__ p2,
                              const float* __restrict__ gt_boxes,
                              const int* __restrict__ gt_classes,
                              const float* __restrict__ anchors,
                              int mb, Smem& sm) {
    int tid = threadIdx.x;
    int wave = tid >> 6, lane = tid & 63;
    int t = mb * 4 + wave;        // 0 .. 3071
    int s = t >> 10;              // scale: 1024 entries per scale
    int e = t & 1023;             // (b, m) flat
    int b = e >> 5;

    float cx = gt_boxes[e * 4 + 0];
    float cy = gt_boxes[e * 4 + 1];
    float w  = gt_boxes[e * 4 + 2];
    float h  = gt_boxes[e * 4 + 3];
    int bp = best_prior(anchors, w, h, w * h);
    int a = bp - s * NA;

    float term = 0.0f;
    if (a >= 0 && a < NA) {                       // mask_s (wave-uniform)
        const float* p = (s == 0) ? p0 : ((s == 1) ? p1 : p2);
        int G = (s == 0) ? 13 : ((s == 1) ? 26 : 52);
        long nboff = (s == 0) ? 0L : ((s == 1) ? 16224L : 81120L);
        int GG = G * G;

        float gxf = fminf(fmaxf(floorf(cx * (float)G), 0.0f), (float)(G - 1));
        float gyf = fminf(fmaxf(floorf(cy * (float)G), 0.0f), (float)(G - 1));
        int gx = (int)gxf, gy = (int)gyf;
        int box_idx = a * GG + gy * G + gx;
        long gidx = nboff + (long)b * (NA * GG) + box_idx;
        if (gidx != 0) {                          // valid (wave-uniform)
            float dx = cx * (float)G - gxf;
            float dy = cy * (float)G - gyf;
            float wgt = 2.0f - w * h;
            float twt = logf(fmaxf(w, FEPS)) - logf(anchors[bp * 2 + 0]);
            float tht = logf(fmaxf(h, FEPS)) - logf(anchors[bp * 2 + 1]);
            int cls = gt_classes[e];

            size_t cellbase = (size_t)(b * (NA * NCH) + a * NCH) * GG
                              + (size_t)(gy * G + gx);
            for (int ch = lane; ch < NCH; ch += 64) {
                float val = p[cellbase + (size_t)ch * GG];
                if (ch < 2) {
                    float sv = sigmoidf_(val);
                    float d = sv - (ch == 0 ? dx : dy);
                    term += L_COORD * wgt * d * d;
                } else if (ch < 4) {
                    float d = val - (ch == 2 ? twt : tht);
                    term += L_COORD * wgt * d * d;
                } else if (ch == 4) {
                    float sv = sigmoidf_(val);
                    term += (sv - 1.0f) * (sv - 1.0f);
                } else {
                    float sv = sigmoidf_(val);
                    float oh = ((ch - 5) == cls) ? 1.0f : 0.0f;
                    term += (sv - oh) * (sv - oh);
                }
            }
        }
    }

    // 64-lane wave reduce -> LDS -> block partial
    for (int off = 32; off; off >>= 1) term += __shfl_down(term, off);
    if (lane == 0) sm.wsum[wave] = term;
    __syncthreads();
    return sm.wsum[0] + sm.wsum[1] + sm.wsum[2] + sm.wsum[3];
}

__device__ __forceinline__ float do_task(int task,
        const float* __restrict__ p0, const float* __restrict__ p1,
        const float* __restrict__ p2, const float* __restrict__ gt_boxes,
        const int* __restrict__ gt_classes, const float* __restrict__ anchors,
        Smem& sm) {
    if (task < OFF1)      return noobj_body<13, 0>(p0, gt_boxes, anchors, task, sm);
    else if (task < OFF2) return noobj_body<26, 1>(p1, gt_boxes, anchors, task - OFF1, sm);
    else if (task < OFFM) return noobj_body<52, 2>(p2, gt_boxes, anchors, task - OFF2, sm);
    else return matched_body(p0, p1, p2, gt_boxes, gt_classes, anchors, task - OFFM, sm);
}

// ---------------------------------------------------------------------------
// Single dispatch, relaxed-atomics-only completion (no release/acquire fences,
// no wbL2/invL2, no grid barrier):
//  - block 0: if flag != MAGIC (first call on poisoned ws): cnt=0, acc=0,
//    vmcnt(0), flag=MAGIC. Flag stays MAGIC forever after.
//  - every block: 4 grid-stride tasks -> one relaxed atomicAdd(acc, partial)
//    (device-scope RMW serializes at the coherence point -> acts as the
//    flush), s_waitcnt vmcnt(0), then relaxed fetch_add(cnt, 1).
//  - the block whose cnt-return == NBLK-1 is last: every block's acc-RMW
//    completed before its cnt-RMW issued, so an RMW-read of acc now returns
//    the full sum. Stores out[0], resets acc=0/cnt=0 for the next replay
//    (EOP flush orders these before the next graph launch).
//  - workers check flag only AFTER their compute -> in practice zero spin
//    iterations; bounded spin makes a hang impossible regardless.
// ---------------------------------------------------------------------------
__global__ __launch_bounds__(256)
void yolo_one(const float* __restrict__ p0, const float* __restrict__ p1,
              const float* __restrict__ p2, const float* __restrict__ gt_boxes,
              const int* __restrict__ gt_classes, const float* __restrict__ anchors,
              float* __restrict__ ws, float* __restrict__ out) {
    float* acc = ws + ACC_IDX;
    unsigned* cnt = (unsigned*)(ws + CNT_IDX);
    unsigned long long* flag = (unsigned long long*)(ws + FLAG_IDX);
    int bid = blockIdx.x, tid = threadIdx.x;

    if (bid == 0 && tid == 0) {
        if (__hip_atomic_load(flag, __ATOMIC_RELAXED, __HIP_MEMORY_SCOPE_AGENT)
                != FLAG_MAGIC) {
            __hip_atomic_store(cnt, 0u, __ATOMIC_RELAXED, __HIP_MEMORY_SCOPE_AGENT);
            __hip_atomic_store(acc, 0.0f, __ATOMIC_RELAXED, __HIP_MEMORY_SCOPE_AGENT);
            asm volatile("s_waitcnt vmcnt(0)" ::: "memory");
            __hip_atomic_store(flag, FLAG_MAGIC, __ATOMIC_RELAXED, __HIP_MEMORY_SCOPE_AGENT);
        }
    }

    __shared__ Smem sm;
    float part = 0.0f;
    for (int task = bid; task < TOTAL_TASKS; task += NBLK) {
        part += do_task(task, p0, p1, p2, gt_boxes, gt_classes, anchors, sm);
        __syncthreads();   // sm reuse across tasks
    }

    if (tid != 0) return;

    // first-call gate: ensure cnt/acc were zeroed before contributing.
    long spins = 0;
    while (__hip_atomic_load(flag, __ATOMIC_RELAXED, __HIP_MEMORY_SCOPE_AGENT)
               != FLAG_MAGIC && spins < (1L << 20)) {
        __builtin_amdgcn_s_sleep(1);
        ++spins;
    }

    float oldacc = __hip_atomic_fetch_add(acc, part, __ATOMIC_RELAXED,
                                          __HIP_MEMORY_SCOPE_AGENT);
    asm volatile("s_waitcnt vmcnt(0)" :: "v"(oldacc) : "memory");  // acc RMW globally done
    unsigned oldcnt = __hip_atomic_fetch_add(cnt, 1u, __ATOMIC_RELAXED,
                                             __HIP_MEMORY_SCOPE_AGENT);
    if (oldcnt == (unsigned)(NBLK - 1)) {
        // last block: total-order on acc guarantees this RMW sees all adds
        float tot = __hip_atomic_fetch_add(acc, 0.0f, __ATOMIC_RELAXED,
                                           __HIP_MEMORY_SCOPE_AGENT);
        out[0] = tot;
        // reset for next replay (EOP flush publishes before next dispatch)
        __hip_atomic_store(acc, 0.0f, __ATOMIC_RELAXED, __HIP_MEMORY_SCOPE_AGENT);
        __hip_atomic_store(cnt, 0u, __ATOMIC_RELAXED, __HIP_MEMORY_SCOPE_AGENT);
    }
}

// ---------------------------------------------------------------------------
extern "C" void kernel_launch(void* const* d_in, const int* in_sizes, int n_in,
                              void* d_out, int out_size, void* d_ws, size_t ws_size,
                              hipStream_t stream) {
    const float* p0 = (const float*)d_in[0];
    const float* p1 = (const float*)d_in[1];
    const float* p2 = (const float*)d_in[2];
    const float* gt_boxes = (const float*)d_in[3];
    const int* gt_classes = (const int*)d_in[4];
    const float* anchors = (const float*)d_in[5];
    float* out = (float*)d_out;
    float* ws = (float*)d_ws;

    yolo_one<<<NBLK, 256, 0, stream>>>(p0, p1, p2, gt_boxes,
                                       gt_classes, anchors, ws, out);
}

// Round 7
// 17.849 us; speedup vs baseline: 6.6319x; 3.0660x over previous
//
#include <hip/hip_runtime.h>
#include <math.h>
#include <float.h>

#define NB 32          // batch
#define NM 32          // max GT per image
#define NA 3           // anchors per scale
#define NCLS 80
#define NCH 85         // 5 + C
#define IOU_THR 0.7f
#define L_COORD 0.75f
#define FEPS 1e-8f

// task layout
#define NOOBJ0_TASKS (NB * NA * 1)    // G=13: 169 -> 1 chunk of 256
#define NOOBJ1_TASKS (NB * NA * 3)    // G=26: 676 -> 3 chunks
#define NOOBJ2_TASKS (NB * NA * 11)   // G=52: 2704 -> 11 chunks
#define OFF1 (NOOBJ0_TASKS)                        // 96
#define OFF2 (OFF1 + NOOBJ1_TASKS)                 // 384
#define OFFM (OFF2 + NOOBJ2_TASKS)                 // 1440
#define MATCHED_TASKS (3 * NB * NM / 4)            // 3072 wave-tasks / 4 waves = 768
#define TOTAL_TASKS (OFFM + MATCHED_TASKS)         // 2208

struct Smem {
    float4 sbox[NM];            // GT x1,y1,x2,y2
    float  sarea[NM];           // GT area (w*h)
    int    scode[NM];           // matched-cell code for this scale, or -1
    int    slist[NM];           // compacted IoU-candidate GT indices
    int    clist[NM];           // compacted matched-cell pix codes for this (b,a)
    float  wmin[4], wmax[4];
    int    scnt, ccnt;
    float  wsum[4];
};

__device__ __forceinline__ float sigmoidf_(float x) {
    return 1.0f / (1.0f + expf(-x));
}

// argmax over 9 anchors of min-intersection IoU (first-max tie, like jnp.argmax)
__device__ __forceinline__ int best_prior(const float* __restrict__ anchors,
                                          float w, float h, float area_g) {
    float best = -1.0f;
    int bp = 0;
    #pragma unroll
    for (int k = 0; k < 9; ++k) {
        float aw = anchors[k * 2 + 0];
        float ah = anchors[k * 2 + 1];
        float inter = fminf(w, aw) * fminf(h, ah);
        float uni = area_g + aw * ah - inter;
        float r = inter / (uni + FEPS);
        if (r > best) { best = r; bp = k; }
    }
    return bp;
}

// ---------------------------------------------------------------------------
// noobj body with exact candidate filtering:
//  - IoU(a,b) <= min(A,B)/max(A,B): a GT can only produce IoU>0.7 for cells
//    of this block if its area is within ~[0.7,1/0.7] of the block's
//    [min,max] predicted-box area (1.02x conservative slack -> never prunes
//    a true positive).
//  - matched-cell codes filtered to this block's (scale,anchor).
// Full IoU runs only over the compacted candidate list.
// ---------------------------------------------------------------------------
template <int G, int S>
__device__ float noobj_body(const float* __restrict__ p,
                            const float* __restrict__ gt_boxes,
                            const float* __restrict__ anchors,
                            int bid, Smem& sm) {
    constexpr int GG = G * G;
    constexpr int CHUNKS = (GG + 255) / 256;

    int chunk = bid % CHUNKS;
    int a = (bid / CHUNKS) % NA;
    int b = bid / (CHUNKS * NA);
    int tid = threadIdx.x;
    int lane = tid & 63, wid = tid >> 6;

    // GT prep (one wave's first 32 lanes)
    if (tid < NM) {
        int e = b * NM + tid;
        float cx = gt_boxes[e * 4 + 0];
        float cy = gt_boxes[e * 4 + 1];
        float w  = gt_boxes[e * 4 + 2];
        float h  = gt_boxes[e * 4 + 3];
        float x1 = cx - w * 0.5f, y1 = cy - h * 0.5f;
        float x2 = cx + w * 0.5f, y2 = cy + h * 0.5f;
        sm.sbox[tid] = make_float4(x1, y1, x2, y2);
        sm.sarea[tid] = (x2 - x1) * (y2 - y1);
        int bp = best_prior(anchors, w, h, w * h);
        int code = -1;
        if (bp >= S * NA && bp < S * NA + NA) {
            float gxf = fminf(fmaxf(floorf(cx * (float)G), 0.0f), (float)(G - 1));
            float gyf = fminf(fmaxf(floorf(cy * (float)G), 0.0f), (float)(G - 1));
            code = (bp - S * NA) * GG + (int)gyf * G + (int)gxf;
        }
        sm.scode[tid] = code;
    }

    // cell decode
    float aw = anchors[(S * NA + a) * 2 + 0];
    float ah = anchors[(S * NA + a) * 2 + 1];
    int pix = chunk * 256 + tid;
    bool live = pix < GG;
    float bx1 = 0.f, by1 = 0.f, bx2 = 0.f, by2 = 0.f, areab = 0.f, to = 0.f;
    if (live) {
        int gy = pix / G, gx = pix % G;
        const float* base = p + (size_t)(b * (NA * NCH) + a * NCH) * GG + pix;
        float tx = base[0];
        float ty = base[(size_t)GG];
        float tw = base[2 * (size_t)GG];
        float th = base[3 * (size_t)GG];
        to = base[4 * (size_t)GG];

        float bcx = (sigmoidf_(tx) + (float)gx) / (float)G;
        float bcy = (sigmoidf_(ty) + (float)gy) / (float)G;
        float bw = aw * expf(tw);
        float bh = ah * expf(th);
        bx1 = bcx - bw * 0.5f; by1 = bcy - bh * 0.5f;
        bx2 = bcx + bw * 0.5f; by2 = bcy + bh * 0.5f;
        areab = (bx2 - bx1) * (by2 - by1);
    }

    // block min/max of areab (valid cells only)
    float mn = live ? areab : FLT_MAX;
    float mx = live ? areab : 0.0f;
    #pragma unroll
    for (int off = 32; off; off >>= 1) {
        mn = fminf(mn, __shfl_xor(mn, off));
        mx = fmaxf(mx, __shfl_xor(mx, off));
    }
    if (lane == 0) { sm.wmin[wid] = mn; sm.wmax[wid] = mx; }
    __syncthreads();   // (1) GT smem + wave min/max ready

    // wave 0 compacts candidate lists
    if (tid < 64) {
        float bmin = fminf(fminf(sm.wmin[0], sm.wmin[1]), fminf(sm.wmin[2], sm.wmin[3]));
        float bmax = fmaxf(fmaxf(sm.wmax[0], sm.wmax[1]), fmaxf(sm.wmax[2], sm.wmax[3]));
        bool c_win = false, c_code = false;
        int cellcode = 0;
        if (tid < NM) {
            float Am = sm.sarea[tid];
            // conservative area window: 1.02*min(A,B) > 0.7*max(A,B) possible
            c_win = (1.02f * bmax > IOU_THR * Am) && (1.02f * Am > IOU_THR * bmin);
            int code = sm.scode[tid];
            c_code = (code >= a * GG) && (code < (a + 1) * GG);   // code==-1 fails
            cellcode = code - a * GG;
        }
        unsigned long long mwin = __ballot(c_win);
        unsigned long long mcode = __ballot(c_code);
        unsigned long long below = (1ull << tid) - 1;
        if (c_win)  sm.slist[__popcll(mwin & below)] = tid;
        if (c_code) sm.clist[__popcll(mcode & below)] = cellcode;
        if (tid == 0) { sm.scnt = (int)__popcll(mwin); sm.ccnt = (int)__popcll(mcode); }
    }
    __syncthreads();   // (2) lists ready

    int pos = 0;
    int sc = sm.scnt, cc = sm.ccnt;
    for (int j = 0; j < cc; ++j)
        pos |= (sm.clist[j] == pix);          // matched-cell override
    for (int j = 0; j < sc; ++j) {
        int m = sm.slist[j];
        float4 bb = sm.sbox[m];
        float ltx = fmaxf(bb.x, bx1), lty = fmaxf(bb.y, by1);
        float rbx = fminf(bb.z, bx2), rby = fminf(bb.w, by2);
        float wx = fmaxf(rbx - ltx, 0.0f), wy = fmaxf(rby - lty, 0.0f);
        float inter = wx * wy;
        float denom = sm.sarea[m] + areab - inter + FEPS;
        pos |= (inter > IOU_THR * denom);     // identical arithmetic to R3
    }

    float local = 0.0f;
    if (live && !pos) {
        float so = sigmoidf_(to);
        local = so * so;
    }

    // block reduce: wave shuffle -> LDS
    for (int off = 32; off; off >>= 1) local += __shfl_down(local, off);
    if (lane == 0) sm.wsum[wid] = local;
    __syncthreads();
    return sm.wsum[0] + sm.wsum[1] + sm.wsum[2] + sm.wsum[3];
}

// ---------------------------------------------------------------------------
// matched body: one wave per (scale, b, m) entry; 4 waves per task.
// Lane covers channels {lane, lane+64}. Returns block partial. (Unchanged.)
// ---------------------------------------------------------------------------
__device__ float matched_body(const float* __restrict__ p0,
                              const float* __restrict__ p1,
                              const float* __restrict__ p2,
                              const float* __restrict__ gt_boxes,
                              const int* __restrict__ gt_classes,
                              const float* __restrict__ anchors,
                              int mb, Smem& sm) {
    int tid = threadIdx.x;
    int wave = tid >> 6, lane = tid & 63;
    int t = mb * 4 + wave;        // 0 .. 3071
    int s = t >> 10;              // scale: 1024 entries per scale
    int e = t & 1023;             // (b, m) flat
    int b = e >> 5;

    float cx = gt_boxes[e * 4 + 0];
    float cy = gt_boxes[e * 4 + 1];
    float w  = gt_boxes[e * 4 + 2];
    float h  = gt_boxes[e * 4 + 3];
    int bp = best_prior(anchors, w, h, w * h);
    int a = bp - s * NA;

    float term = 0.0f;
    if (a >= 0 && a < NA) {                       // mask_s (wave-uniform)
        const float* p = (s == 0) ? p0 : ((s == 1) ? p1 : p2);
        int G = (s == 0) ? 13 : ((s == 1) ? 26 : 52);
        long nboff = (s == 0) ? 0L : ((s == 1) ? 16224L : 81120L);
        int GG = G * G;

        float gxf = fminf(fmaxf(floorf(cx * (float)G), 0.0f), (float)(G - 1));
        float gyf = fminf(fmaxf(floorf(cy * (float)G), 0.0f), (float)(G - 1));
        int gx = (int)gxf, gy = (int)gyf;
        int box_idx = a * GG + gy * G + gx;
        long gidx = nboff + (long)b * (NA * GG) + box_idx;
        if (gidx != 0) {                          // valid (wave-uniform)
            float dx = cx * (float)G - gxf;
            float dy = cy * (float)G - gyf;
            float wgt = 2.0f - w * h;
            float twt = logf(fmaxf(w, FEPS)) - logf(anchors[bp * 2 + 0]);
            float tht = logf(fmaxf(h, FEPS)) - logf(anchors[bp * 2 + 1]);
            int cls = gt_classes[e];

            size_t cellbase = (size_t)(b * (NA * NCH) + a * NCH) * GG
                              + (size_t)(gy * G + gx);
            for (int ch = lane; ch < NCH; ch += 64) {
                float val = p[cellbase + (size_t)ch * GG];
                if (ch < 2) {
                    float sv = sigmoidf_(val);
                    float d = sv - (ch == 0 ? dx : dy);
                    term += L_COORD * wgt * d * d;
                } else if (ch < 4) {
                    float d = val - (ch == 2 ? twt : tht);
                    term += L_COORD * wgt * d * d;
                } else if (ch == 4) {
                    float sv = sigmoidf_(val);
                    term += (sv - 1.0f) * (sv - 1.0f);
                } else {
                    float sv = sigmoidf_(val);
                    float oh = ((ch - 5) == cls) ? 1.0f : 0.0f;
                    term += (sv - oh) * (sv - oh);
                }
            }
        }
    }

    // 64-lane wave reduce -> LDS -> block partial
    for (int off = 32; off; off >>= 1) term += __shfl_down(term, off);
    if (lane == 0) sm.wsum[wave] = term;
    __syncthreads();
    return sm.wsum[0] + sm.wsum[1] + sm.wsum[2] + sm.wsum[3];
}

__device__ __forceinline__ float do_task(int task,
        const float* __restrict__ p0, const float* __restrict__ p1,
        const float* __restrict__ p2, const float* __restrict__ gt_boxes,
        const int* __restrict__ gt_classes, const float* __restrict__ anchors,
        Smem& sm) {
    if (task < OFF1)      return noobj_body<13, 0>(p0, gt_boxes, anchors, task, sm);
    else if (task < OFF2) return noobj_body<26, 1>(p1, gt_boxes, anchors, task - OFF1, sm);
    else if (task < OFFM) return noobj_body<52, 2>(p2, gt_boxes, anchors, task - OFF2, sm);
    else return matched_body(p0, p1, p2, gt_boxes, gt_classes, anchors, task - OFFM, sm);
}

// ---------------------------------------------------------------------------
// Proven 2-node structure (R3): fused partials + tiny reduce.
// ---------------------------------------------------------------------------
__global__ __launch_bounds__(256)
void yolo_fused(const float* __restrict__ p0, const float* __restrict__ p1,
                const float* __restrict__ p2, const float* __restrict__ gt_boxes,
                const int* __restrict__ gt_classes, const float* __restrict__ anchors,
                float* __restrict__ partials) {
    __shared__ Smem sm;
    float part = do_task(blockIdx.x, p0, p1, p2, gt_boxes, gt_classes, anchors, sm);
    if (threadIdx.x == 0) partials[blockIdx.x] = part;
}

__global__ __launch_bounds__(256)
void yolo_reduce(const float* __restrict__ partials, float* __restrict__ out) {
    int tid = threadIdx.x;
    float s = 0.0f;
    for (int i = tid; i < TOTAL_TASKS; i += 256) s += partials[i];
    for (int off = 32; off; off >>= 1) s += __shfl_down(s, off);
    __shared__ float wsum[4];
    if ((tid & 63) == 0) wsum[tid >> 6] = s;
    __syncthreads();
    if (tid == 0) out[0] = wsum[0] + wsum[1] + wsum[2] + wsum[3];
}

// ---------------------------------------------------------------------------
extern "C" void kernel_launch(void* const* d_in, const int* in_sizes, int n_in,
                              void* d_out, int out_size, void* d_ws, size_t ws_size,
                              hipStream_t stream) {
    const float* p0 = (const float*)d_in[0];
    const float* p1 = (const float*)d_in[1];
    const float* p2 = (const float*)d_in[2];
    const float* gt_boxes = (const float*)d_in[3];
    const int* gt_classes = (const int*)d_in[4];
    const float* anchors = (const float*)d_in[5];
    float* out = (float*)d_out;
    float* partials = (float*)d_ws;

    yolo_fused<<<TOTAL_TASKS, 256, 0, stream>>>(p0, p1, p2, gt_boxes,
                                                gt_classes, anchors, partials);
    yolo_reduce<<<1, 256, 0, stream>>>(partials, out);
}